// Round 2
// baseline (2406.095 us; speedup 1.0000x reference)
//
#include <hip/hip_runtime.h>

#define Bb 64
#define Tt 2048
#define Ii 64
#define Hh 128
#define Gg 384   // 3*H
#define Oo 64

typedef _Float16 f16;
typedef float v2f __attribute__((ext_vector_type(2)));

// ---------------- K1: x-projection  xg[row,g] = dot(x[row,:], W_ih[g,:]) + b_ih[g]
__global__ __launch_bounds__(384, 2) void xproj_kernel(
    const float* __restrict__ inputs, const float* __restrict__ W_ih,
    const float* __restrict__ b_ih, f16* __restrict__ xR, f16* __restrict__ xZN,
    int rowsPerBlock)
{
    __shared__ __align__(16) float xs[16 * 64];
    const int tid = threadIdx.x;

    float wi[64];
#pragma unroll
    for (int k = 0; k < 64; ++k) wi[k] = W_ih[(size_t)tid * 64 + k];
#pragma unroll
    for (int k = 0; k < 64; ++k) asm volatile("" : "+v"(wi[k]));
    const float bi = b_ih[tid];

    const int rowBase = blockIdx.x * rowsPerBlock;
    for (int c = 0; c < rowsPerBlock; c += 16) {
        __syncthreads();
        for (int idx = tid; idx < 16 * 64; idx += 384)
            xs[idx] = inputs[(size_t)(rowBase + c) * 64 + idx];
        __syncthreads();
#pragma unroll 4
        for (int rr = 0; rr < 16; ++rr) {
            const int row = rowBase + c + rr;
            const float4* x4 = (const float4*)&xs[rr * 64];
            float a0 = bi, a1 = 0.f, a2 = 0.f, a3 = 0.f;
#pragma unroll
            for (int i = 0; i < 16; ++i) {
                float4 v = x4[i];
                a0 = fmaf(v.x, wi[4 * i + 0], a0);
                a1 = fmaf(v.y, wi[4 * i + 1], a1);
                a2 = fmaf(v.z, wi[4 * i + 2], a2);
                a3 = fmaf(v.w, wi[4 * i + 3], a3);
            }
            const float acc = (a0 + a1) + (a2 + a3);
            if (tid < 128) xR[(size_t)row * 128 + tid] = (f16)acc;
            else           xZN[(size_t)row * 256 + (tid - 128)] = (f16)acc;
        }
    }
}

// ---------------- K2: sequential GRU recurrence. One block per batch element.
// 768 threads = 12 waves (3/SIMD). Two threads per gate row g = tid>>1:
// thread half = tid&1 owns k in [half*64, half*64+64), w in registers (32 VGPR pairs).
// Pair-sum via __shfl_xor(.,1). h broadcast from LDS (2-address b128 reads = free).
__global__ __launch_bounds__(768, 3) void gru_kernel(
    const float* __restrict__ W_hh, const float* __restrict__ b_hh,
    const f16* __restrict__ xR, const f16* __restrict__ xZN,
    float* __restrict__ latents)
{
    __shared__ __align__(16) float hf[Hh];
    __shared__ float rs[Hh];
    __shared__ float zs[Hh];

    const int tid  = threadIdx.x;
    const int g    = tid >> 1;     // gate row 0..383
    const int half = tid & 1;      // k-half
    const int b    = blockIdx.x;

    // 64 weights per thread as 32 float2 (v_pk_fma_f32 operands), pinned in VGPRs.
    v2f w[32];
    {
        const v2f* wrow = (const v2f*)(W_hh + (size_t)g * Hh + half * 64);
#pragma unroll
        for (int k = 0; k < 32; ++k) w[k] = wrow[k];
#pragma unroll
        for (int k = 0; k < 32; ++k) asm volatile("" : "+v"(w[k]));
    }
    const float bh = b_hh[g];

    if (tid < Hh) hf[tid] = 0.f;

    // per-row x_proj stream (b_ih already folded in by K1)
    const f16* xq;
    int xstride;
    if (g < 128) { xq = xR  + (size_t)b * Tt * 128 + g;         xstride = 128; }
    else         { xq = xZN + (size_t)b * Tt * 256 + (g - 128); xstride = 256; }
    float* lat = latents + (size_t)b * Tt * Hh;

    float xcur = (float)xq[0];
    __syncthreads();

    for (int t = 0; t < Tt; ++t) {
        // prefetch next step's x (1 full step of latency distance)
        float xnext = 0.f;
        if (t + 1 < Tt) xnext = (float)xq[(size_t)(t + 1) * xstride];

        // dot over this thread's k-half: 16 x {ds_read_b128 + 2 v_pk_fma_f32}
        const float4* h4 = (const float4*)&hf[half * 64];
        v2f aA = {0.f, 0.f}, aB = {0.f, 0.f}, aC = {0.f, 0.f}, aD = {0.f, 0.f};
#pragma unroll
        for (int i = 0; i < 8; ++i) {
            float4 v0 = h4[2 * i];
            float4 v1 = h4[2 * i + 1];
            v2f l0 = {v0.x, v0.y}, h0 = {v0.z, v0.w};
            v2f l1 = {v1.x, v1.y}, h1 = {v1.z, v1.w};
            aA = __builtin_elementwise_fma(l0, w[4 * i + 0], aA);
            aB = __builtin_elementwise_fma(h0, w[4 * i + 1], aB);
            aC = __builtin_elementwise_fma(l1, w[4 * i + 2], aC);
            aD = __builtin_elementwise_fma(h1, w[4 * i + 3], aD);
        }
        v2f s = (aA + aB) + (aC + aD);
        float acc = s.x + s.y;
        acc += __shfl_xor(acc, 1, 64);   // pair k-halves; both lanes get full sum

        // phase 1: r,z gates
        if (half == 0 && g < 256) {
            const float p  = acc + bh + xcur;
            const float sg = 1.f / (1.f + __expf(-p));
            if (g < 128) rs[g] = sg;
            else         zs[g - 128] = sg;
        }
        __syncthreads();

        // phase 2: n = tanh(xn + r*hn); h' = (1-z)*n + z*h
        if (half == 0 && g >= 256) {
            const int j   = g - 256;
            const float r = rs[j];
            const float z = zs[j];
            const float hp = hf[j];
            const float a = xcur + r * (acc + bh);
            const float e = __expf(2.f * a);
            const float n = 1.f - 2.f / (e + 1.f);   // tanh, NaN-free
            const float hnew = n + z * (hp - n);
            hf[j] = hnew;
            lat[(size_t)t * Hh + j] = hnew;
        }
        __syncthreads();
        xcur = xnext;
    }
}

// ---------------- K3: out[row,o] = dot(latents[row,:], W_out[o,:]) + b_out[o]
__global__ __launch_bounds__(256, 1) void outproj_kernel(
    const float* __restrict__ latents, const float* __restrict__ W_out,
    const float* __restrict__ b_out, float* __restrict__ out, int rowsPerWave)
{
    const int lane = threadIdx.x & 63;
    const int wave = threadIdx.x >> 6;

    float w[128];
#pragma unroll
    for (int k = 0; k < 128; ++k) w[k] = W_out[(size_t)lane * 128 + k];
#pragma unroll
    for (int k = 0; k < 128; ++k) asm volatile("" : "+v"(w[k]));
    const float bo = b_out[lane];

    const int waveId  = blockIdx.x * 4 + wave;
    const int rowBase = waveId * rowsPerWave;

    for (int rr = 0; rr < rowsPerWave; ++rr) {
        const int row = rowBase + rr;
        const float4* l4 = (const float4*)(latents + (size_t)row * 128);
        float a0 = bo, a1 = 0.f, a2 = 0.f, a3 = 0.f;
#pragma unroll
        for (int i = 0; i < 32; ++i) {
            float4 v = l4[i];
            a0 = fmaf(v.x, w[4 * i + 0], a0);
            a1 = fmaf(v.y, w[4 * i + 1], a1);
            a2 = fmaf(v.z, w[4 * i + 2], a2);
            a3 = fmaf(v.w, w[4 * i + 3], a3);
        }
        out[(size_t)row * 64 + lane] = (a0 + a1) + (a2 + a3);
    }
}

extern "C" void kernel_launch(void* const* d_in, const int* in_sizes, int n_in,
                              void* d_out, int out_size, void* d_ws, size_t ws_size,
                              hipStream_t stream) {
    const float* inputs = (const float*)d_in[0];
    const float* W_ih   = (const float*)d_in[1];
    const float* W_hh   = (const float*)d_in[2];
    const float* b_ih   = (const float*)d_in[3];
    const float* b_hh   = (const float*)d_in[4];
    const float* W_out  = (const float*)d_in[5];
    const float* b_out  = (const float*)d_in[6];

    float* out     = (float*)d_out;
    float* latents = out + (size_t)Bb * Tt * Oo;

    // x_proj staging (f16): r-gates [B*T*128], z+n-gates [B*T*256].
    const size_t xbytes = (size_t)Bb * Tt * Gg * sizeof(f16);  // 100,663,296 B
    f16 *xR, *xZN;
    if (ws_size >= xbytes) {
        xR  = (f16*)d_ws;
        xZN = xR + (size_t)Bb * Tt * Hh;
    } else {
        // Alias into d_out (see R0 note): r-gates fit exactly in the output
        // region, z/n-gates in the latents region; K2's step-t latents writes
        // only touch bytes already consumed (prefetch distance = 1 step).
        xR  = (f16*)d_out;
        xZN = (f16*)latents;
    }

    xproj_kernel<<<512, 384, 0, stream>>>(inputs, W_ih, b_ih, xR, xZN,
                                          (Bb * Tt) / 512);
    gru_kernel<<<Bb, 768, 0, stream>>>(W_hh, b_hh, xR, xZN, latents);
    outproj_kernel<<<512, 256, 0, stream>>>(latents, W_out, b_out, out, 64);
}

// Round 3
// 2279.146 us; speedup vs baseline: 1.0557x; 1.0557x over previous
//
#include <hip/hip_runtime.h>

#define Bb 64
#define Tt 2048
#define Ii 64
#define Hh 128
#define Gg 384   // 3*H
#define Oo 64

typedef _Float16 f16;
typedef float v2f __attribute__((ext_vector_type(2)));
typedef _Float16 half8 __attribute__((ext_vector_type(8)));
typedef float f32x4 __attribute__((ext_vector_type(4)));

// ---------------- K1: x-projection  xg[row,g] = dot(x[row,:], W_ih[g,:]) + b_ih[g]
__global__ __launch_bounds__(384, 2) void xproj_kernel(
    const float* __restrict__ inputs, const float* __restrict__ W_ih,
    const float* __restrict__ b_ih, f16* __restrict__ xR, f16* __restrict__ xZN,
    int rowsPerBlock)
{
    __shared__ __align__(16) float xs[16 * 64];
    const int tid = threadIdx.x;

    float wi[64];
#pragma unroll
    for (int k = 0; k < 64; ++k) wi[k] = W_ih[(size_t)tid * 64 + k];
#pragma unroll
    for (int k = 0; k < 64; ++k) asm volatile("" : "+v"(wi[k]));
    const float bi = b_ih[tid];

    const int rowBase = blockIdx.x * rowsPerBlock;
    for (int c = 0; c < rowsPerBlock; c += 16) {
        __syncthreads();
        for (int idx = tid; idx < 16 * 64; idx += 384)
            xs[idx] = inputs[(size_t)(rowBase + c) * 64 + idx];
        __syncthreads();
#pragma unroll 4
        for (int rr = 0; rr < 16; ++rr) {
            const int row = rowBase + c + rr;
            const float4* x4 = (const float4*)&xs[rr * 64];
            float a0 = bi, a1 = 0.f, a2 = 0.f, a3 = 0.f;
#pragma unroll
            for (int i = 0; i < 16; ++i) {
                float4 v = x4[i];
                a0 = fmaf(v.x, wi[4 * i + 0], a0);
                a1 = fmaf(v.y, wi[4 * i + 1], a1);
                a2 = fmaf(v.z, wi[4 * i + 2], a2);
                a3 = fmaf(v.w, wi[4 * i + 3], a3);
            }
            const float acc = (a0 + a1) + (a2 + a3);
            if (tid < 128) xR[(size_t)row * 128 + tid] = (f16)acc;
            else           xZN[(size_t)row * 256 + (tid - 128)] = (f16)acc;
        }
    }
}

// ---------------- K2: MFMA recurrence. 4 blocks x 512 threads; 16 batches/block.
// Per step: [16,128] @ W_hh^T -> [16,384] via mfma_f32_16x16x32_f16.
// Wave w owns j-range [16w,16w+16) for ALL 3 gates (tiles g=j0, 128+j0, 256+j0),
// so r/z/n for one (b,j) are lane-local. W_hh in VGPRs (f16 B-frags) for the
// whole kernel. LDS only redistributes h' (16x128 f16, XOR-swizzled rows).
__global__ __launch_bounds__(512, 2) void gru_mfma(
    const float* __restrict__ W_hh, const float* __restrict__ b_hh,
    const f16* __restrict__ xR, const f16* __restrict__ xZN,
    float* __restrict__ latents)
{
    __shared__ __align__(16) unsigned char hsm[16 * 256];  // 16 x 128 f16, swizzled

    const int tid = threadIdx.x;
    const int w   = tid >> 6;
    const int l   = tid & 63;
    const int lo  = l & 15;   // C col (=g within tile) / A row (=batch) on reads
    const int hi  = l >> 4;   // k-group
    const int j0  = w * 16;
    const int jj  = j0 + lo;              // this lane's hidden column
    const int bb0 = blockIdx.x * 16;      // batch base

    // B fragments: B[k][n=g], lane lo -> col, hi -> k-chunk of 8.
    // Source: W_hh[g][k] row-major, 8 consecutive k per fragment reg.
    half8 Bf[3][4];
#pragma unroll
    for (int gt = 0; gt < 3; ++gt)
#pragma unroll
        for (int ks = 0; ks < 4; ++ks) {
            const float* wp = W_hh + (size_t)(gt * 128 + jj) * 128 + ks * 32 + hi * 8;
            half8 hv;
#pragma unroll
            for (int q = 0; q < 8; ++q) hv[q] = (f16)wp[q];
            Bf[gt][ks] = hv;
        }
#pragma unroll
    for (int gt = 0; gt < 3; ++gt)
#pragma unroll
        for (int ks = 0; ks < 4; ++ks)
            asm volatile("" : "+v"(Bf[gt][ks]));

    const float br = b_hh[jj];
    const float bz = b_hh[128 + jj];
    const float bn = b_hh[256 + jj];

    // x-stream pointers for this lane's 4 batches b = bb0 + 4*hi + i, col jj.
    const f16* xrp[4];
    const f16* xzp[4];
    float*     latp[4];
#pragma unroll
    for (int i = 0; i < 4; ++i) {
        const size_t b = (size_t)(bb0 + 4 * hi + i);
        xrp[i]  = xR  + b * Tt * 128 + jj;
        xzp[i]  = xZN + b * Tt * 256 + jj;
        latp[i] = latents + b * Tt * 128 + jj;
    }

    // 2-deep x prefetch: set A serves even t, set B serves odd t.
    f16 xrA[4], xzA[4], xnA[4], xrB[4], xzB[4], xnB[4];
#pragma unroll
    for (int i = 0; i < 4; ++i) {
        xrA[i] = xrp[i][0];
        xzA[i] = xzp[i][0];
        xnA[i] = xzp[i][128];
        xrB[i] = xrp[i][128];
        xzB[i] = xzp[i][256];
        xnB[i] = xzp[i][256 + 128];
    }

    float hreg[4] = {0.f, 0.f, 0.f, 0.f};
    half8 A[4];
    {
        half8 z8 = {};
#pragma unroll
        for (int ks = 0; ks < 4; ++ks) A[ks] = z8;
    }

#define GSTEP(T, XRS, XZS, XNS)                                                  \
    {                                                                            \
        const int t_ = (T);                                                      \
        /* consume current x set into f32, then refill it for t+2 */             \
        float xr_[4], xz_[4], xn_[4];                                            \
        _Pragma("unroll") for (int i = 0; i < 4; ++i) {                          \
            xr_[i] = (float)XRS[i]; xz_[i] = (float)XZS[i]; xn_[i] = (float)XNS[i]; \
        }                                                                        \
        if (t_ + 2 < Tt) {                                                       \
            _Pragma("unroll") for (int i = 0; i < 4; ++i) {                      \
                XRS[i] = xrp[i][(size_t)(t_ + 2) * 128];                         \
                XZS[i] = xzp[i][(size_t)(t_ + 2) * 256];                         \
                XNS[i] = xzp[i][(size_t)(t_ + 2) * 256 + 128];                   \
            }                                                                    \
        }                                                                        \
        f32x4 accr = {br, br, br, br};                                           \
        f32x4 accz = {bz, bz, bz, bz};                                           \
        f32x4 accn = {bn, bn, bn, bn};                                           \
        _Pragma("unroll") for (int ks = 0; ks < 4; ++ks) {                       \
            accr = __builtin_amdgcn_mfma_f32_16x16x32_f16(A[ks], Bf[0][ks], accr, 0, 0, 0); \
            accz = __builtin_amdgcn_mfma_f32_16x16x32_f16(A[ks], Bf[1][ks], accz, 0, 0, 0); \
            accn = __builtin_amdgcn_mfma_f32_16x16x32_f16(A[ks], Bf[2][ks], accn, 0, 0, 0); \
        }                                                                        \
        _Pragma("unroll") for (int i = 0; i < 4; ++i) {                          \
            const float r  = __builtin_amdgcn_rcpf(1.f + __expf(-(accr[i] + xr_[i]))); \
            const float z  = __builtin_amdgcn_rcpf(1.f + __expf(-(accz[i] + xz_[i]))); \
            const float a  = xn_[i] + r * accn[i];                               \
            const float n  = 1.f - 2.f * __builtin_amdgcn_rcpf(__expf(2.f * a) + 1.f); \
            const float hnew = n + z * (hreg[i] - n);                            \
            hreg[i] = hnew;                                                      \
            latp[i][(size_t)t_ * 128] = hnew;                                    \
            const int b  = 4 * hi + i;                                           \
            const int wa = (b * 256 + (jj << 1)) ^ ((b & 7) << 4);               \
            *(f16*)(hsm + wa) = (f16)hnew;                                       \
        }                                                                        \
        __syncthreads();                                                         \
        _Pragma("unroll") for (int ks = 0; ks < 4; ++ks) {                       \
            const int ra = (lo * 256 + hi * 16 + ks * 64) ^ ((lo & 7) << 4);     \
            A[ks] = *(const half8*)(hsm + ra);                                   \
        }                                                                        \
        __syncthreads();                                                         \
    }

    for (int t = 0; t < Tt; t += 2) {
        GSTEP(t,     xrA, xzA, xnA)
        GSTEP(t + 1, xrB, xzB, xnB)
    }
#undef GSTEP
}

// ---------------- K3: out[row,o] = dot(latents[row,:], W_out[o,:]) + b_out[o]
__global__ __launch_bounds__(256, 1) void outproj_kernel(
    const float* __restrict__ latents, const float* __restrict__ W_out,
    const float* __restrict__ b_out, float* __restrict__ out, int rowsPerWave)
{
    const int lane = threadIdx.x & 63;
    const int wave = threadIdx.x >> 6;

    float w[128];
#pragma unroll
    for (int k = 0; k < 128; ++k) w[k] = W_out[(size_t)lane * 128 + k];
#pragma unroll
    for (int k = 0; k < 128; ++k) asm volatile("" : "+v"(w[k]));
    const float bo = b_out[lane];

    const int waveId  = blockIdx.x * 4 + wave;
    const int rowBase = waveId * rowsPerWave;

    for (int rr = 0; rr < rowsPerWave; ++rr) {
        const int row = rowBase + rr;
        const float4* l4 = (const float4*)(latents + (size_t)row * 128);
        float a0 = bo, a1 = 0.f, a2 = 0.f, a3 = 0.f;
#pragma unroll
        for (int i = 0; i < 32; ++i) {
            float4 v = l4[i];
            a0 = fmaf(v.x, w[4 * i + 0], a0);
            a1 = fmaf(v.y, w[4 * i + 1], a1);
            a2 = fmaf(v.z, w[4 * i + 2], a2);
            a3 = fmaf(v.w, w[4 * i + 3], a3);
        }
        out[(size_t)row * 64 + lane] = (a0 + a1) + (a2 + a3);
    }
}

extern "C" void kernel_launch(void* const* d_in, const int* in_sizes, int n_in,
                              void* d_out, int out_size, void* d_ws, size_t ws_size,
                              hipStream_t stream) {
    const float* inputs = (const float*)d_in[0];
    const float* W_ih   = (const float*)d_in[1];
    const float* W_hh   = (const float*)d_in[2];
    const float* b_ih   = (const float*)d_in[3];
    const float* b_hh   = (const float*)d_in[4];
    const float* W_out  = (const float*)d_in[5];
    const float* b_out  = (const float*)d_in[6];

    float* out     = (float*)d_out;
    float* latents = out + (size_t)Bb * Tt * Oo;

    // x_proj staging (f16): r-gates [B][T][128], z+n-gates [B][T][256].
    const size_t xbytes = (size_t)Bb * Tt * Gg * sizeof(f16);  // 100,663,296 B
    f16 *xR, *xZN;
    if (ws_size >= xbytes) {
        xR  = (f16*)d_ws;
        xZN = xR + (size_t)Bb * Tt * Hh;
    } else {
        // Alias into d_out: xR fits exactly in the output region, xZN exactly in
        // the latents region. K2's latents write at (b,t) lands on xZN row (b,t),
        // which was consumed at prefetch two steps earlier; x reads are always
        // for t+2 > t. K3 overwrites the output region only after K2 completes.
        xR  = (f16*)d_out;
        xZN = (f16*)latents;
    }

    xproj_kernel<<<512, 384, 0, stream>>>(inputs, W_ih, b_ih, xR, xZN,
                                          (Bb * Tt) / 512);
    gru_mfma<<<4, 512, 0, stream>>>(W_hh, b_hh, xR, xZN, latents);
    outproj_kernel<<<512, 256, 0, stream>>>(latents, W_out, b_out, out, 64);
}

// Round 5
// 1977.988 us; speedup vs baseline: 1.2164x; 1.1523x over previous
//
#include <hip/hip_runtime.h>

#define Bb 64
#define Tt 2048
#define Ii 64
#define Hh 128
#define Gg 384   // 3*H
#define Oo 64

typedef _Float16 f16;
typedef _Float16 half8 __attribute__((ext_vector_type(8)));
typedef _Float16 half2v __attribute__((ext_vector_type(2)));
typedef __fp16 fp16v2 __attribute__((ext_vector_type(2)));   // cvt_pkrtz native type
typedef float f32x4 __attribute__((ext_vector_type(4)));

// ---------------- K1: x-projection  xg[row,g] = dot(x[row,:], W_ih[g,:]) + b_ih[g]
__global__ __launch_bounds__(384, 2) void xproj_kernel(
    const float* __restrict__ inputs, const float* __restrict__ W_ih,
    const float* __restrict__ b_ih, f16* __restrict__ xR, f16* __restrict__ xZN,
    int rowsPerBlock)
{
    __shared__ __align__(16) float xs[16 * 64];
    const int tid = threadIdx.x;

    float wi[64];
#pragma unroll
    for (int k = 0; k < 64; ++k) wi[k] = W_ih[(size_t)tid * 64 + k];
#pragma unroll
    for (int k = 0; k < 64; ++k) asm volatile("" : "+v"(wi[k]));
    const float bi = b_ih[tid];

    const int rowBase = blockIdx.x * rowsPerBlock;
    for (int c = 0; c < rowsPerBlock; c += 16) {
        __syncthreads();
        for (int idx = tid; idx < 16 * 64; idx += 384)
            xs[idx] = inputs[(size_t)(rowBase + c) * 64 + idx];
        __syncthreads();
#pragma unroll 4
        for (int rr = 0; rr < 16; ++rr) {
            const int row = rowBase + c + rr;
            const float4* x4 = (const float4*)&xs[rr * 64];
            float a0 = bi, a1 = 0.f, a2 = 0.f, a3 = 0.f;
#pragma unroll
            for (int i = 0; i < 16; ++i) {
                float4 v = x4[i];
                a0 = fmaf(v.x, wi[4 * i + 0], a0);
                a1 = fmaf(v.y, wi[4 * i + 1], a1);
                a2 = fmaf(v.z, wi[4 * i + 2], a2);
                a3 = fmaf(v.w, wi[4 * i + 3], a3);
            }
            const float acc = (a0 + a1) + (a2 + a3);
            if (tid < 128) xR[(size_t)row * 128 + tid] = (f16)acc;
            else           xZN[(size_t)row * 256 + (tid - 128)] = (f16)acc;
        }
    }
}

// ---------------- K2: MFMA recurrence. 4 blocks x 512 threads; 16 batches/block.
// h' ping-pong LDS in A-FRAGMENT ORDER: slot(b,kc)=((kc>>2)*1024+(kc&3)*256+b*16);
// read = ds_read_b128 at ks*1024 + (l>>4)*256 + (l&15)*16 -> conflict-free 8-sweep.
// Writes: j-pair pack via shfl_xor(1)+cvt_pkrtz, even lanes ds_write_b32.
// One barrier per step (ping-pong parity proof in journal).
__global__ __launch_bounds__(512, 2) void gru_mfma(
    const float* __restrict__ W_hh, const float* __restrict__ b_hh,
    const f16* __restrict__ xR, const f16* __restrict__ xZN,
    float* __restrict__ latents)
{
    __shared__ __align__(16) unsigned char hsm[2][4096];

    const int tid = threadIdx.x;
    const int w   = tid >> 6;
    const int l   = tid & 63;
    const int lo  = l & 15;   // C col (j within tile) / A row (batch) on reads
    const int hi  = l >> 4;
    const int jj  = w * 16 + lo;          // this lane's hidden column
    const int bb0 = blockIdx.x * 16;      // batch base

    // B fragments: lane lo -> col jj, hi -> k-chunk of 8; 8 consecutive k per reg.
    half8 Bf[3][4];
#pragma unroll
    for (int gt = 0; gt < 3; ++gt)
#pragma unroll
        for (int ks = 0; ks < 4; ++ks) {
            const float* wp = W_hh + (size_t)(gt * 128 + jj) * 128 + ks * 32 + hi * 8;
            half8 hv;
#pragma unroll
            for (int q = 0; q < 8; ++q) hv[q] = (f16)wp[q];
            Bf[gt][ks] = hv;
        }
#pragma unroll
    for (int gt = 0; gt < 3; ++gt)
#pragma unroll
        for (int ks = 0; ks < 4; ++ks)
            asm volatile("" : "+v"(Bf[gt][ks]));

    const float br = b_hh[jj];
    const float bz = b_hh[128 + jj];
    const float bn = b_hh[256 + jj];

    // x-stream pointers for this lane's 4 batches b = bb0 + 4*hi + i, col jj.
    const f16* xrp[4];
    const f16* xzp[4];
    float*     latp[4];
#pragma unroll
    for (int i = 0; i < 4; ++i) {
        const size_t b = (size_t)(bb0 + 4 * hi + i);
        xrp[i]  = xR  + b * Tt * 128 + jj;
        xzp[i]  = xZN + b * Tt * 256 + jj;
        latp[i] = latents + b * Tt * 128 + jj;
    }

    // LDS addresses: read base (add ks*1024), write base (add i*16; even lo only).
    const int rbase = hi * 256 + lo * 16;
    const int wbase = (w >> 1) * 1024 + ((2 * w + (lo >> 3)) & 3) * 256
                    + hi * 64 + (lo & 7) * 2;

    // 2-deep x prefetch: set A serves even t, set B serves odd t.
    f16 xrA[4], xzA[4], xnA[4], xrB[4], xzB[4], xnB[4];
#pragma unroll
    for (int i = 0; i < 4; ++i) {
        xrA[i] = xrp[i][0];
        xzA[i] = xzp[i][0];
        xnA[i] = xzp[i][128];
        xrB[i] = xrp[i][128];
        xzB[i] = xzp[i][256];
        xnB[i] = xzp[i][256 + 128];
    }

    float hreg[4] = {0.f, 0.f, 0.f, 0.f};
    half8 A[4];
    {
        half8 z8 = {};
#pragma unroll
        for (int ks = 0; ks < 4; ++ks) A[ks] = z8;
    }

#define GSTEP(T, WP, XRS, XZS, XNS)                                              \
    {                                                                            \
        const int t_ = (T);                                                      \
        float xr_[4], xz_[4], xn_[4];                                            \
        _Pragma("unroll") for (int i = 0; i < 4; ++i) {                          \
            xr_[i] = (float)XRS[i]; xz_[i] = (float)XZS[i]; xn_[i] = (float)XNS[i]; \
        }                                                                        \
        if (t_ + 2 < Tt) {                                                       \
            _Pragma("unroll") for (int i = 0; i < 4; ++i) {                      \
                XRS[i] = xrp[i][(size_t)(t_ + 2) * 128];                         \
                XZS[i] = xzp[i][(size_t)(t_ + 2) * 256];                         \
                XNS[i] = xzp[i][(size_t)(t_ + 2) * 256 + 128];                   \
            }                                                                    \
        }                                                                        \
        f32x4 accr = {br, br, br, br};                                           \
        f32x4 accz = {bz, bz, bz, bz};                                           \
        f32x4 accn = {bn, bn, bn, bn};                                           \
        _Pragma("unroll") for (int ks = 0; ks < 4; ++ks) {                       \
            accr = __builtin_amdgcn_mfma_f32_16x16x32_f16(A[ks], Bf[0][ks], accr, 0, 0, 0); \
            accz = __builtin_amdgcn_mfma_f32_16x16x32_f16(A[ks], Bf[1][ks], accz, 0, 0, 0); \
            accn = __builtin_amdgcn_mfma_f32_16x16x32_f16(A[ks], Bf[2][ks], accn, 0, 0, 0); \
        }                                                                        \
        float hnew[4];                                                           \
        _Pragma("unroll") for (int i = 0; i < 4; ++i) {                          \
            const float r  = __builtin_amdgcn_rcpf(1.f + __expf(-(accr[i] + xr_[i]))); \
            const float z  = __builtin_amdgcn_rcpf(1.f + __expf(-(accz[i] + xz_[i]))); \
            const float a  = xn_[i] + r * accn[i];                               \
            const float n  = 1.f - 2.f * __builtin_amdgcn_rcpf(__expf(2.f * a) + 1.f); \
            hnew[i] = n + z * (hreg[i] - n);                                     \
            hreg[i] = hnew[i];                                                   \
            latp[i][(size_t)t_ * 128] = hnew[i];                                 \
        }                                                                        \
        half2v pk[4];                                                            \
        _Pragma("unroll") for (int i = 0; i < 4; ++i) {                          \
            const float other = __shfl_xor(hnew[i], 1);                          \
            fp16v2 pknative = __builtin_amdgcn_cvt_pkrtz(hnew[i], other);        \
            pk[i] = __builtin_bit_cast(half2v, pknative);                        \
        }                                                                        \
        if (!(lo & 1)) {                                                         \
            _Pragma("unroll") for (int i = 0; i < 4; ++i)                        \
                *(half2v*)(&hsm[WP][wbase + i * 16]) = pk[i];                    \
        }                                                                        \
        __syncthreads();                                                         \
        _Pragma("unroll") for (int ks = 0; ks < 4; ++ks)                         \
            A[ks] = *(const half8*)(&hsm[WP][rbase + ks * 1024]);                \
    }

    for (int t = 0; t < Tt; t += 2) {
        GSTEP(t,     0, xrA, xzA, xnA)
        GSTEP(t + 1, 1, xrB, xzB, xnB)
    }
#undef GSTEP
}

// ---------------- K3: out[row,o] = dot(latents[row,:], W_out[o,:]) + b_out[o]
__global__ __launch_bounds__(256, 1) void outproj_kernel(
    const float* __restrict__ latents, const float* __restrict__ W_out,
    const float* __restrict__ b_out, float* __restrict__ out, int rowsPerWave)
{
    const int lane = threadIdx.x & 63;
    const int wave = threadIdx.x >> 6;

    float w[128];
#pragma unroll
    for (int k = 0; k < 128; ++k) w[k] = W_out[(size_t)lane * 128 + k];
#pragma unroll
    for (int k = 0; k < 128; ++k) asm volatile("" : "+v"(w[k]));
    const float bo = b_out[lane];

    const int waveId  = blockIdx.x * 4 + wave;
    const int rowBase = waveId * rowsPerWave;

    for (int rr = 0; rr < rowsPerWave; ++rr) {
        const int row = rowBase + rr;
        const float4* l4 = (const float4*)(latents + (size_t)row * 128);
        float a0 = bo, a1 = 0.f, a2 = 0.f, a3 = 0.f;
#pragma unroll
        for (int i = 0; i < 32; ++i) {
            float4 v = l4[i];
            a0 = fmaf(v.x, w[4 * i + 0], a0);
            a1 = fmaf(v.y, w[4 * i + 1], a1);
            a2 = fmaf(v.z, w[4 * i + 2], a2);
            a3 = fmaf(v.w, w[4 * i + 3], a3);
        }
        out[(size_t)row * 64 + lane] = (a0 + a1) + (a2 + a3);
    }
}

extern "C" void kernel_launch(void* const* d_in, const int* in_sizes, int n_in,
                              void* d_out, int out_size, void* d_ws, size_t ws_size,
                              hipStream_t stream) {
    const float* inputs = (const float*)d_in[0];
    const float* W_ih   = (const float*)d_in[1];
    const float* W_hh   = (const float*)d_in[2];
    const float* b_ih   = (const float*)d_in[3];
    const float* b_hh   = (const float*)d_in[4];
    const float* W_out  = (const float*)d_in[5];
    const float* b_out  = (const float*)d_in[6];

    float* out     = (float*)d_out;
    float* latents = out + (size_t)Bb * Tt * Oo;

    // x_proj staging (f16): r-gates [B][T][128], z+n-gates [B][T][256].
    const size_t xbytes = (size_t)Bb * Tt * Gg * sizeof(f16);  // 100,663,296 B
    f16 *xR, *xZN;
    if (ws_size >= xbytes) {
        xR  = (f16*)d_ws;
        xZN = xR + (size_t)Bb * Tt * Hh;
    } else {
        // Alias into d_out: xR fits exactly in the output region, xZN exactly in
        // the latents region. K2's latents write at (b,t) lands on xZN row (b,t),
        // consumed two steps earlier (prefetch distance 2); x reads are always
        // for t+2. K3 overwrites the output region only after K2 completes.
        xR  = (f16*)d_out;
        xZN = (f16*)latents;
    }

    xproj_kernel<<<512, 384, 0, stream>>>(inputs, W_ih, b_ih, xR, xZN,
                                          (Bb * Tt) / 512);
    gru_mfma<<<4, 512, 0, stream>>>(W_hh, b_hh, xR, xZN, latents);
    outproj_kernel<<<512, 256, 0, stream>>>(latents, W_out, b_out, out, 64);
}

// Round 6
// 1291.793 us; speedup vs baseline: 1.8626x; 1.5312x over previous
//
#include <hip/hip_runtime.h>

#define Bb 64
#define Tt 2048
#define Ii 64
#define Hh 128
#define Gg 384   // 3*H
#define Oo 64

typedef _Float16 f16;
typedef _Float16 half8 __attribute__((ext_vector_type(8)));
typedef __fp16 fp16v2 __attribute__((ext_vector_type(2)));   // cvt_pkrtz native type
typedef float f32x4 __attribute__((ext_vector_type(4)));
typedef unsigned int u32;

static __device__ __forceinline__ float cvt_lo(u32 u) {
    fp16v2 v = __builtin_bit_cast(fp16v2, u);
    return (float)v[0];
}
static __device__ __forceinline__ float cvt_hi(u32 u) {
    fp16v2 v = __builtin_bit_cast(fp16v2, u);
    return (float)v[1];
}

// ---------------- K1: x-projection  xg[row,g] = dot(x[row,:], W_ih[g,:]) + b_ih[g]
// Layout: xR[row][j] = r-gate; xZN[row][2j] = z-gate, xZN[row][2j+1] = n-gate
// (z,n interleaved so K2's eval lane fetches both with one dword load).
__global__ __launch_bounds__(384, 2) void xproj_kernel(
    const float* __restrict__ inputs, const float* __restrict__ W_ih,
    const float* __restrict__ b_ih, f16* __restrict__ xR, f16* __restrict__ xZN,
    int rowsPerBlock)
{
    __shared__ __align__(16) float xs[16 * 64];
    const int tid = threadIdx.x;

    float wi[64];
#pragma unroll
    for (int k = 0; k < 64; ++k) wi[k] = W_ih[(size_t)tid * 64 + k];
#pragma unroll
    for (int k = 0; k < 64; ++k) asm volatile("" : "+v"(wi[k]));
    const float bi = b_ih[tid];

    const int rowBase = blockIdx.x * rowsPerBlock;
    for (int c = 0; c < rowsPerBlock; c += 16) {
        __syncthreads();
        for (int idx = tid; idx < 16 * 64; idx += 384)
            xs[idx] = inputs[(size_t)(rowBase + c) * 64 + idx];
        __syncthreads();
#pragma unroll 4
        for (int rr = 0; rr < 16; ++rr) {
            const int row = rowBase + c + rr;
            const float4* x4 = (const float4*)&xs[rr * 64];
            float a0 = bi, a1 = 0.f, a2 = 0.f, a3 = 0.f;
#pragma unroll
            for (int i = 0; i < 16; ++i) {
                float4 v = x4[i];
                a0 = fmaf(v.x, wi[4 * i + 0], a0);
                a1 = fmaf(v.y, wi[4 * i + 1], a1);
                a2 = fmaf(v.z, wi[4 * i + 2], a2);
                a3 = fmaf(v.w, wi[4 * i + 3], a3);
            }
            const float acc = (a0 + a1) + (a2 + a3);
            if (tid < 128)      xR[(size_t)row * 128 + tid] = (f16)acc;
            else if (tid < 256) xZN[(size_t)row * 256 + 2 * (tid - 128)] = (f16)acc;
            else                xZN[(size_t)row * 256 + 2 * (tid - 256) + 1] = (f16)acc;
        }
    }
}

// ---------------- K2: MFMA recurrence. 16 blocks x 512 threads; 4 batches/block.
// Per step: [4,128] @ W_hh^T (16-row MFMA tile, rows 4-15 zero). Valid C values
// land in lanes hi=0 (regs=batch); redistribute via cvt_pkrtz(f16-pair) +
// ds_bpermute(src lane = lo) so every lane evals exactly ONE (b=hi, j) gate set.
// h' exchange: same A-fragment-order LDS slots, pack-pair b32 writes, ping-pong,
// 1 barrier/step (HW-validated in R5).
__global__ __launch_bounds__(512, 2) void gru_mfma(
    const float* __restrict__ W_hh, const float* __restrict__ b_hh,
    const f16* __restrict__ xR, const f16* __restrict__ xZN,
    float* __restrict__ latents)
{
    __shared__ __align__(16) unsigned char hsm[2][4096];

    const int tid = threadIdx.x;
    const int w   = tid >> 6;
    const int l   = tid & 63;
    const int lo  = l & 15;
    const int hi  = l >> 4;
    const int jj  = w * 16 + lo;          // this lane's hidden column
    const int bb0 = blockIdx.x * 4;       // batch base (4 per block)

    // Zero both buffers once: A rows b>=4 are never written and must stay 0.
    {
        float4 z4 = {0.f, 0.f, 0.f, 0.f};
        ((float4*)hsm)[tid] = z4;   // 512 threads x 16B = 8192B exactly
    }

    // B fragments: lane lo -> col jj, hi -> k-chunk of 8; 8 consecutive k per reg.
    half8 Bf[3][4];
#pragma unroll
    for (int gt = 0; gt < 3; ++gt)
#pragma unroll
        for (int ks = 0; ks < 4; ++ks) {
            const float* wp = W_hh + (size_t)(gt * 128 + jj) * 128 + ks * 32 + hi * 8;
            half8 hv;
#pragma unroll
            for (int q = 0; q < 8; ++q) hv[q] = (f16)wp[q];
            Bf[gt][ks] = hv;
        }
#pragma unroll
    for (int gt = 0; gt < 3; ++gt)
#pragma unroll
        for (int ks = 0; ks < 4; ++ks)
            asm volatile("" : "+v"(Bf[gt][ks]));

    const float br = b_hh[jj];
    const float bz = b_hh[128 + jj];
    const float bn = b_hh[256 + jj];

    // Eval-lane streams: this lane owns (b = bb0 + hi, j = jj).
    const f16* xrp  = xR  + (size_t)(bb0 + hi) * Tt * 128 + jj;
    const f16* xznp = xZN + (size_t)(bb0 + hi) * Tt * 256 + 2 * jj;
    float*     latp = latents + (size_t)(bb0 + hi) * Tt * 128 + jj;

    const int srcAddr = lo << 2;               // bpermute byte index (lane lo)
    const int rbase   = hi * 256 + lo * 16;    // A-frag read base (+ ks*1024)
    const int wbase   = (w >> 1) * 1024 + (((w & 1) * 2 + (lo >> 3)) & 3) * 256
                      + hi * 16 + (lo & 6) * 2;  // h' write base (even lo lanes)

    // 2-deep x prefetch: set A serves even t, set B serves odd t.
    f16 xrA = xrp[0];
    f16 xrB = xrp[128];
    u32 xzA = *(const u32*)xznp;
    u32 xzB = *(const u32*)(xznp + 256);

    float hreg = 0.f;
    half8 A[4];
    {
        half8 z8 = {};
#pragma unroll
        for (int ks = 0; ks < 4; ++ks) A[ks] = z8;
    }
    __syncthreads();   // LDS zero-init visible before any step-0 h' write

#define GSTEP(T, WP, XRC, XZC)                                                   \
    {                                                                            \
        const int t_ = (T);                                                      \
        const float xr_ = (float)XRC;                                            \
        const float xz_ = cvt_lo(XZC);                                           \
        const float xn_ = cvt_hi(XZC);                                           \
        if (t_ + 2 < Tt) {                                                       \
            XRC = xrp[(size_t)(t_ + 2) * 128];                                   \
            XZC = *(const u32*)(xznp + (size_t)(t_ + 2) * 256);                  \
        }                                                                        \
        f32x4 accr = {br, br, br, br};                                           \
        f32x4 accz = {bz, bz, bz, bz};                                           \
        f32x4 accn = {bn, bn, bn, bn};                                           \
        _Pragma("unroll") for (int ks = 0; ks < 4; ++ks) {                       \
            accr = __builtin_amdgcn_mfma_f32_16x16x32_f16(A[ks], Bf[0][ks], accr, 0, 0, 0); \
            accz = __builtin_amdgcn_mfma_f32_16x16x32_f16(A[ks], Bf[1][ks], accz, 0, 0, 0); \
            accn = __builtin_amdgcn_mfma_f32_16x16x32_f16(A[ks], Bf[2][ks], accn, 0, 0, 0); \
        }                                                                        \
        /* pack pre-activations to f16 pairs and broadcast from lanes hi=0 */    \
        int rz0 = __builtin_bit_cast(int, __builtin_amdgcn_cvt_pkrtz(accr[0], accz[0])); \
        int rz1 = __builtin_bit_cast(int, __builtin_amdgcn_cvt_pkrtz(accr[1], accz[1])); \
        int rz2 = __builtin_bit_cast(int, __builtin_amdgcn_cvt_pkrtz(accr[2], accz[2])); \
        int rz3 = __builtin_bit_cast(int, __builtin_amdgcn_cvt_pkrtz(accr[3], accz[3])); \
        int n01 = __builtin_bit_cast(int, __builtin_amdgcn_cvt_pkrtz(accn[0], accn[1])); \
        int n23 = __builtin_bit_cast(int, __builtin_amdgcn_cvt_pkrtz(accn[2], accn[3])); \
        rz0 = __builtin_amdgcn_ds_bpermute(srcAddr, rz0);                        \
        rz1 = __builtin_amdgcn_ds_bpermute(srcAddr, rz1);                        \
        rz2 = __builtin_amdgcn_ds_bpermute(srcAddr, rz2);                        \
        rz3 = __builtin_amdgcn_ds_bpermute(srcAddr, rz3);                        \
        n01 = __builtin_amdgcn_ds_bpermute(srcAddr, n01);                        \
        n23 = __builtin_amdgcn_ds_bpermute(srcAddr, n23);                        \
        const int  rzsel = (hi & 2) ? ((hi & 1) ? rz3 : rz2)                     \
                                    : ((hi & 1) ? rz1 : rz0);                    \
        const int  nsel  = (hi & 2) ? n23 : n01;                                 \
        const u32  nbits = (hi & 1) ? ((u32)nsel >> 16) : (u32)nsel;             \
        const float rpre = cvt_lo((u32)rzsel);                                   \
        const float zpre = cvt_hi((u32)rzsel);                                   \
        const float npre = cvt_lo(nbits);                                        \
        const float r = __builtin_amdgcn_rcpf(1.f + __expf(-(rpre + xr_)));      \
        const float z = __builtin_amdgcn_rcpf(1.f + __expf(-(zpre + xz_)));      \
        const float a = xn_ + r * npre;                                          \
        const float n = 1.f - 2.f * __builtin_amdgcn_rcpf(__expf(2.f * a) + 1.f); \
        const float hnew = n + z * (hreg - n);                                   \
        hreg = hnew;                                                             \
        latp[(size_t)t_ * 128] = hnew;                                           \
        const float other = __shfl_xor(hnew, 1);                                 \
        const fp16v2 pkh = __builtin_amdgcn_cvt_pkrtz(hnew, other);              \
        if (!(l & 1)) *(fp16v2*)(&hsm[WP][wbase]) = pkh;                         \
        __syncthreads();                                                         \
        _Pragma("unroll") for (int ks = 0; ks < 4; ++ks)                         \
            A[ks] = *(const half8*)(&hsm[WP][rbase + ks * 1024]);                \
    }

    for (int t = 0; t < Tt; t += 2) {
        GSTEP(t,     0, xrA, xzA)
        GSTEP(t + 1, 1, xrB, xzB)
    }
#undef GSTEP
}

// ---------------- K3: out[row,o] = dot(latents[row,:], W_out[o,:]) + b_out[o]
__global__ __launch_bounds__(256, 1) void outproj_kernel(
    const float* __restrict__ latents, const float* __restrict__ W_out,
    const float* __restrict__ b_out, float* __restrict__ out, int rowsPerWave)
{
    const int lane = threadIdx.x & 63;
    const int wave = threadIdx.x >> 6;

    float w[128];
#pragma unroll
    for (int k = 0; k < 128; ++k) w[k] = W_out[(size_t)lane * 128 + k];
#pragma unroll
    for (int k = 0; k < 128; ++k) asm volatile("" : "+v"(w[k]));
    const float bo = b_out[lane];

    const int waveId  = blockIdx.x * 4 + wave;
    const int rowBase = waveId * rowsPerWave;

    for (int rr = 0; rr < rowsPerWave; ++rr) {
        const int row = rowBase + rr;
        const float4* l4 = (const float4*)(latents + (size_t)row * 128);
        float a0 = bo, a1 = 0.f, a2 = 0.f, a3 = 0.f;
#pragma unroll
        for (int i = 0; i < 32; ++i) {
            float4 v = l4[i];
            a0 = fmaf(v.x, w[4 * i + 0], a0);
            a1 = fmaf(v.y, w[4 * i + 1], a1);
            a2 = fmaf(v.z, w[4 * i + 2], a2);
            a3 = fmaf(v.w, w[4 * i + 3], a3);
        }
        out[(size_t)row * 64 + lane] = (a0 + a1) + (a2 + a3);
    }
}

extern "C" void kernel_launch(void* const* d_in, const int* in_sizes, int n_in,
                              void* d_out, int out_size, void* d_ws, size_t ws_size,
                              hipStream_t stream) {
    const float* inputs = (const float*)d_in[0];
    const float* W_ih   = (const float*)d_in[1];
    const float* W_hh   = (const float*)d_in[2];
    const float* b_ih   = (const float*)d_in[3];
    const float* b_hh   = (const float*)d_in[4];
    const float* W_out  = (const float*)d_in[5];
    const float* b_out  = (const float*)d_in[6];

    float* out     = (float*)d_out;
    float* latents = out + (size_t)Bb * Tt * Oo;

    // x_proj staging (f16): r-gates [B][T][128]; z/n interleaved [B][T][128][2].
    const size_t xbytes = (size_t)Bb * Tt * Gg * sizeof(f16);  // 100,663,296 B
    f16 *xR, *xZN;
    if (ws_size >= xbytes) {
        xR  = (f16*)d_ws;
        xZN = xR + (size_t)Bb * Tt * Hh;
    } else {
        // Alias into d_out: xR fits exactly in the output region, xZN exactly in
        // the latents region. K2's latents write at (b,t) lands on xZN row (b,t),
        // consumed two steps earlier (prefetch distance 2); x reads are always
        // for t+2. K3 overwrites the output region only after K2 completes.
        xR  = (f16*)d_out;
        xZN = (f16*)latents;
    }

    xproj_kernel<<<1024, 384, 0, stream>>>(inputs, W_ih, b_ih, xR, xZN,
                                           (Bb * Tt) / 1024);
    gru_mfma<<<16, 512, 0, stream>>>(W_hh, b_hh, xR, xZN, latents);
    outproj_kernel<<<1024, 256, 0, stream>>>(latents, W_out, b_out, out, 32);
}